// Round 5
// baseline (1847.066 us; speedup 1.0000x reference)
//
#include <hip/hip_runtime.h>
#include <hip/hip_bf16.h>

#define N_NODES 50000
#define DEG     16
#define IN_CH   128
#define TYPE_DIM 32
#define F_DIM   160      // = IN_CH + TYPE_DIM
#define H_DIM   160
#define OUT_CH  128
#define NSTEP   16       // = DEG timesteps
#define LS      168      // LDS row stride in ushorts (16B-aligned, +8 pad)
#define BROWS   32       // nodes per block
#define NTHR    320      // 5 waves

typedef short  bf16x8 __attribute__((ext_vector_type(8)));
typedef float  f32x4  __attribute__((ext_vector_type(4)));
typedef unsigned int u32x4 __attribute__((ext_vector_type(4)));

// Workspace in __device__ globals (cached VRAM) — d_ws is mapped
// uncached/streaming. Fully rewritten every call.
__device__ ushort g_hin[N_NODES * F_DIM];       // 16,000,000 B
__device__ ushort g_wfrag[400 * 64 * 8];        // 409,600 B
__device__ ushort g_wlrfrag[80 * 64 * 8];       // 81,920 B
__device__ float  g_bsum[4 * H_DIM];            // 2,560 B

static __device__ __forceinline__ ushort f2bf(float v) {
    union { float f; unsigned u; } x; x.f = v;
    unsigned r = x.u + 0x7fff + ((x.u >> 16) & 1);   // RNE
    return (ushort)(r >> 16);
}
// v_rcp_f32 (1 instr) instead of IEEE division (~9 instr): R1 proved real win.
static __device__ __forceinline__ float sigmoid_fast(float x) {
    return __builtin_amdgcn_rcpf(1.f + __expf(-x));
}
static __device__ __forceinline__ float tanh_fast(float x) {
    float e = __expf(2.f * x);
    return 1.f - 2.f * __builtin_amdgcn_rcpf(e + 1.f);
}

// ---------------------------------------------------------------------------
// Pack weights into MFMA B-fragment order (bf16), and sum biases.
// Main W frags: frag = qg*40 + kc*4 + p   (qg 0..9, kc 0..9 K-chunk, p gate)
//   kc<5 -> W_ih (X part), kc>=5 -> W_hh (H part)
// Final W frags: frag = kc*8 + nt : row = nt*16+(lane&15), k<160 -> W_l, else W_r
// ---------------------------------------------------------------------------
__global__ void pack_kernel(const float* __restrict__ Wih, const float* __restrict__ Whh,
                            const float* __restrict__ bih, const float* __restrict__ bhh,
                            const float* __restrict__ Wl,  const float* __restrict__ Wr)
{
    int gid = blockIdx.x * 256 + threadIdx.x;
    if (gid < 400 * 64) {
        int frag = gid >> 6, lane = gid & 63;
        int p = frag & 3, kc = (frag >> 2) % 10, qg = frag / 40;
        int row = p * 160 + qg * 16 + (lane & 15);
        int quad = lane >> 4;
        const float* src; int k0;
        if (kc < 5) { src = Wih + row * 160; k0 = kc * 32 + quad * 8; }
        else        { src = Whh + row * 160; k0 = (kc - 5) * 32 + quad * 8; }
        ushort tmp[8];
        #pragma unroll
        for (int j = 0; j < 8; j++) tmp[j] = f2bf(src[k0 + j]);
        ((u32x4*)g_wfrag)[frag * 64 + lane] = *(const u32x4*)tmp;
    } else if (gid < 400 * 64 + 80 * 64) {
        int g2 = gid - 400 * 64;
        int frag = g2 >> 6, lane = g2 & 63;
        int nt = frag & 7, kc = frag >> 3;
        int row = nt * 16 + (lane & 15);
        int quad = lane >> 4;
        int k0 = kc * 32 + quad * 8;
        ushort tmp[8];
        #pragma unroll
        for (int j = 0; j < 8; j++) {
            int k = k0 + j;
            float v = (k < 160) ? Wl[row * 160 + k] : Wr[row * 160 + (k - 160)];
            tmp[j] = f2bf(v);
        }
        ((u32x4*)g_wlrfrag)[frag * 64 + lane] = *(const u32x4*)tmp;
    } else if (gid < 400 * 64 + 80 * 64 + 640) {
        int i = gid - (400 * 64 + 80 * 64);
        g_bsum[i] = bih[i] + bhh[i];
    }
}

// h_in = concat(x, emb[type]) as bf16 rows of 160 (320 B, 16B aligned)
__global__ void build_hin(const float* __restrict__ x, const int* __restrict__ tids,
                          const float* __restrict__ emb)
{
    int i = blockIdx.x * 256 + threadIdx.x;
    if (i >= N_NODES * F_DIM) return;
    int n = i / F_DIM, d = i - n * F_DIM;
    float v = (d < IN_CH) ? x[n * IN_CH + d] : emb[tids[n] * TYPE_DIM + (d - IN_CH)];
    g_hin[i] = f2bf(v);
}

// ---------------------------------------------------------------------------
// R5: 32-node / 5-wave block, qg-SEQUENTIAL halves to halve the accumulator.
//
// R4 post-mortem (the key diagnostic of the session): occupancy is limited by
// TOTAL regs/wave (VGPR+AGPR, unified file, 512/SIMD pool) x wave-count
// quantization:
//   R1: 84+64=148 -> 3 waves/SIMD -> one 10-wave block only (occ 24%)
//   R4: 128+64=192 -> 2 waves/SIMD -> one 5-wave block only  (occ 13%)
// Fix: wave processes col-group qgA=wv fully (10 kc MFMA + elementwise),
// then qgB=wv+5 REUSING the same acc[2][4] (32 regs). sched_barrier(0x120)
// between halves (VMEM/DS reads may cross; MFMA/VALU may not) keeps the two
// acc lifetimes disjoint so demand stays ~130 total. launch_bounds(320,4)
// caps at 128 total -> 4 waves/SIMD -> THREE independent 5-wave blocks/CU
// whose barriers interleave (the latency hiding that 10-wave convoys never
// got). LDS 21.5KB x3 fits. No forced starvation (R2 lesson: cap ~= demand).
// ---------------------------------------------------------------------------
__launch_bounds__(NTHR, 4)
__global__ void lstm_sage_q(const int* __restrict__ edge_src,
                            const float* __restrict__ bl,
                            float* __restrict__ out)
{
    __shared__ ushort Xb[BROWS * LS];
    __shared__ ushort Hb[BROWS * LS];

    const int tid  = threadIdx.x;
    const int lane = tid & 63;
    const int wv   = tid >> 6;           // 0..4
    const int col  = lane & 15, quad = lane >> 4;
    const int nb   = blockIdx.x * BROWS;

    float bG[2][4];
    #pragma unroll
    for (int q = 0; q < 2; q++)
        #pragma unroll
        for (int p = 0; p < 4; p++)
            bG[q][p] = g_bsum[p * 160 + (wv + 5 * q) * 16 + col];

    for (int i = tid; i < BROWS * LS; i += NTHR) Hb[i] = 0;   // h(-1) = 0

    float c_st[2][2][4];                 // [q][m][r] — all static indexing
    #pragma unroll
    for (int q = 0; q < 2; q++)
        #pragma unroll
        for (int m = 0; m < 2; m++)
            #pragma unroll
            for (int r = 0; r < 4; r++) c_st[q][m][r] = 0.f;

    unsigned hn32[2][2][2];              // [q][m][k] packed bf16 pairs

    const int grow  = tid / 10;          // 32 rows x 10 threads
    const int gpart = tid - grow * 10;   // 0..9 -> chunks gpart, gpart+10
    const int node_g = nb + grow;
    const int own = (node_g < N_NODES ? node_g : 0);
    const int sbase = own * DEG;

    // prologue: park X(0) (plain cacheable loads; ~16x reuse per g_hin row)
    u32x4 P0, P1;
    {
        int s = edge_src[sbase];
        const u32x4* sp = (const u32x4*)(g_hin + s * F_DIM);
        P0 = sp[gpart]; P1 = sp[gpart + 10];
    }
    int snext = edge_src[sbase + 1];

    const int aoff = col * LS + quad * 8;          // A-frag base (rows 0..15)

    #pragma unroll 1
    for (int t = 0; t < NSTEP; t++) {
        // commit h(t-1) regs and parked gather X(t) to LDS
        if (t > 0) {
            #pragma unroll
            for (int q = 0; q < 2; q++)
                #pragma unroll
                for (int m = 0; m < 2; m++)
                    #pragma unroll
                    for (int k = 0; k < 2; k++) {
                        int a = (m * 16 + quad * 4 + 2 * k) * LS + (wv + 5 * q) * 16 + col;
                        unsigned pk = hn32[q][m][k];
                        Hb[a]      = (ushort)pk;
                        Hb[a + LS] = (ushort)(pk >> 16);
                    }
        }
        {
            u32x4* dp = (u32x4*)(Xb + grow * LS);
            dp[gpart] = P0; dp[gpart + 10] = P1;
        }
        __syncthreads();

        // park next gather (t=15: own h_in row for the epilogue)
        {
            const u32x4* sp = (t < NSTEP - 1)
                ? (const u32x4*)(g_hin + snext * F_DIM)
                : (const u32x4*)(g_hin + own * F_DIM);
            P0 = sp[gpart]; P1 = sp[gpart + 10];
            snext = edge_src[sbase + ((t + 2 < DEG) ? t + 2 : 0)];
        }

        // two qg halves, SEQUENTIAL, one shared 32-reg accumulator
        #pragma unroll
        for (int q = 0; q < 2; q++) {
            const u32x4* wq = (const u32x4*)g_wfrag + (wv + 5 * q) * (40 * 64) + lane;

            f32x4 acc[2][4];
            #pragma unroll
            for (int m = 0; m < 2; m++)
                #pragma unroll
                for (int p = 0; p < 4; p++)
                    acc[m][p] = (f32x4){bG[q][p], bG[q][p], bG[q][p], bG[q][p]};

            #pragma unroll
            for (int kc = 0; kc < 10; kc++) {
                bf16x8 bfr[4];
                #pragma unroll
                for (int p = 0; p < 4; p++) {
                    u32x4 u = wq[(kc * 4 + p) * 64];
                    bfr[p] = *(const bf16x8*)&u;
                }
                const ushort* ab = ((kc < 5) ? (Xb + kc * 32) : (Hb + (kc - 5) * 32)) + aoff;
                bf16x8 afr[2];
                #pragma unroll
                for (int m = 0; m < 2; m++)
                    afr[m] = *(const bf16x8*)(ab + m * (16 * LS));
                #pragma unroll
                for (int m = 0; m < 2; m++)
                    #pragma unroll
                    for (int p = 0; p < 4; p++)
                        acc[m][p] = __builtin_amdgcn_mfma_f32_16x16x32_bf16(
                            afr[m], bfr[p], acc[m][p], 0, 0, 0);
            }

            // elementwise -> h(t) staged in regs (committed next loop top)
            #pragma unroll
            for (int m = 0; m < 2; m++)
                #pragma unroll
                for (int k = 0; k < 2; k++) {
                    unsigned pk = 0;
                    #pragma unroll
                    for (int h2 = 0; h2 < 2; h2++) {
                        int r = 2 * k + h2;
                        float c = sigmoid_fast(acc[m][1][r]) * c_st[q][m][r]
                                + sigmoid_fast(acc[m][0][r]) * tanh_fast(acc[m][2][r]);
                        c_st[q][m][r] = c;
                        float h = sigmoid_fast(acc[m][3][r]) * tanh_fast(c);
                        pk |= ((unsigned)f2bf(h)) << (16 * h2);
                    }
                    hn32[q][m][k] = pk;
                }

            // keep the two halves' acc lifetimes disjoint (register plan),
            // while letting VMEM reads (0x20) and DS reads (0x100) cross so
            // q=1's weight/A loads hide under q=0's elementwise.
            if (q == 0) __builtin_amdgcn_sched_barrier(0x120);
        }
        __syncthreads();
    }

    // final commit: Hb = h(15), Xb = own h_in rows (parked at t=15)
    #pragma unroll
    for (int q = 0; q < 2; q++)
        #pragma unroll
        for (int m = 0; m < 2; m++)
            #pragma unroll
            for (int k = 0; k < 2; k++) {
                int a = (m * 16 + quad * 4 + 2 * k) * LS + (wv + 5 * q) * 16 + col;
                unsigned pk = hn32[q][m][k];
                Hb[a]      = (ushort)pk;
                Hb[a + LS] = (ushort)(pk >> 16);
            }
    {
        u32x4* dp = (u32x4*)(Xb + grow * LS);
        dp[gpart] = P0; dp[gpart + 10] = P1;
    }
    __syncthreads();

    // out = relu([h_last | h_in] @ [W_l | W_r]^T + b_l)
    // waves 0..3: nt pair {2wv, 2wv+1}, both m tiles; wave 4 idle.
    if (wv < 4) {
        const int nt0 = wv * 2;
        f32x4 acc2[2][2];                // [m][j]  (nt = nt0+j)
        #pragma unroll
        for (int j = 0; j < 2; j++) {
            float b = bl[(nt0 + j) * 16 + col];
            acc2[0][j] = (f32x4){b, b, b, b};
            acc2[1][j] = (f32x4){b, b, b, b};
        }
        const u32x4* wq2 = (const u32x4*)g_wlrfrag + lane;
        #pragma unroll
        for (int kc = 0; kc < 10; kc++) {
            bf16x8 bfr[2];
            #pragma unroll
            for (int j = 0; j < 2; j++) {
                u32x4 u = wq2[(kc * 8 + nt0 + j) * 64];
                bfr[j] = *(const bf16x8*)&u;
            }
            const int bk = (kc < 5) ? kc : (kc - 5);
            const ushort* base = (kc < 5) ? Hb : Xb;   // h_last | h_in order
            #pragma unroll
            for (int m = 0; m < 2; m++) {
                const ushort* ab = base + bk * 32 + (m * 16 + col) * LS + quad * 8;
                bf16x8 afr = *(const bf16x8*)ab;
                #pragma unroll
                for (int j = 0; j < 2; j++)
                    acc2[m][j] = __builtin_amdgcn_mfma_f32_16x16x32_bf16(
                        afr, bfr[j], acc2[m][j], 0, 0, 0);
            }
        }
        #pragma unroll
        for (int m = 0; m < 2; m++)
            #pragma unroll
            for (int j = 0; j < 2; j++) {
                int ocol = (nt0 + j) * 16 + col;
                #pragma unroll
                for (int r = 0; r < 4; r++) {
                    int node = nb + m * 16 + quad * 4 + r;
                    if (node < N_NODES) {
                        float v = acc2[m][j][r];
                        out[node * OUT_CH + ocol] = v > 0.f ? v : 0.f;
                    }
                }
            }
    }
}

extern "C" void kernel_launch(void* const* d_in, const int* in_sizes, int n_in,
                              void* d_out, int out_size, void* d_ws, size_t ws_size,
                              hipStream_t stream)
{
    const float* x      = (const float*)d_in[0];
    const int*   tids   = (const int*)  d_in[1];
    const int*   esrc   = (const int*)  d_in[2];   // edge_index[0] = src (dst sorted, DEG each)
    const float* emb    = (const float*)d_in[3];
    const float* Wih    = (const float*)d_in[4];
    const float* Whh    = (const float*)d_in[5];
    const float* bih    = (const float*)d_in[6];
    const float* bhh    = (const float*)d_in[7];
    const float* Wl     = (const float*)d_in[8];
    const float* blin   = (const float*)d_in[9];
    const float* Wr     = (const float*)d_in[10];
    float* out = (float*)d_out;

    hipLaunchKernelGGL(pack_kernel, dim3(123), dim3(256), 0, stream,
                       Wih, Whh, bih, bhh, Wl, Wr);
    hipLaunchKernelGGL(build_hin, dim3((N_NODES * F_DIM + 255) / 256), dim3(256), 0, stream,
                       x, tids, emb);

    hipLaunchKernelGGL(lstm_sage_q, dim3((N_NODES + BROWS - 1) / BROWS), dim3(NTHR),
                       0, stream, esrc, blin, out);
}

// Round 6
// 1207.204 us; speedup vs baseline: 1.5300x; 1.5300x over previous
//
#include <hip/hip_runtime.h>
#include <hip/hip_bf16.h>

#define N_NODES 50000
#define DEG     16
#define IN_CH   128
#define TYPE_DIM 32
#define F_DIM   160      // = IN_CH + TYPE_DIM
#define H_DIM   160
#define OUT_CH  128
#define NSTEP   16       // = DEG timesteps
#define LS      168      // LDS row stride in ushorts (16B-aligned)

typedef short  bf16x8 __attribute__((ext_vector_type(8)));
typedef float  f32x4  __attribute__((ext_vector_type(4)));
typedef unsigned int u32x4 __attribute__((ext_vector_type(4)));

// Workspace in __device__ globals (cached VRAM) — d_ws is mapped
// uncached/streaming. Fully rewritten every call.
__device__ ushort g_hin[N_NODES * F_DIM];       // 16,000,000 B
__device__ ushort g_wfrag[400 * 64 * 8];        // 409,600 B
__device__ ushort g_wlrfrag[80 * 64 * 8];       // 81,920 B
__device__ float  g_bsum[4 * H_DIM];            // 2,560 B

static __device__ __forceinline__ ushort f2bf(float v) {
    union { float f; unsigned u; } x; x.f = v;
    unsigned r = x.u + 0x7fff + ((x.u >> 16) & 1);   // RNE
    return (ushort)(r >> 16);
}
// v_rcp_f32 (1 instr) instead of IEEE division (~9 instr): R1 proved real win.
static __device__ __forceinline__ float sigmoid_fast(float x) {
    return __builtin_amdgcn_rcpf(1.f + __expf(-x));
}
static __device__ __forceinline__ float tanh_fast(float x) {
    float e = __expf(2.f * x);
    return 1.f - 2.f * __builtin_amdgcn_rcpf(e + 1.f);
}

// ---------------------------------------------------------------------------
// Pack weights into MFMA B-fragment order (bf16), and sum biases.
// Main W frags: frag = qg*40 + kc*4 + p   (qg 0..9, kc 0..9 K-chunk, p gate)
//   kc<5 -> W_ih (X part), kc>=5 -> W_hh (H part)
// Final W frags: frag = kc*8 + nt : row = nt*16+(lane&15), k<160 -> W_l, else W_r
// ---------------------------------------------------------------------------
__global__ void pack_kernel(const float* __restrict__ Wih, const float* __restrict__ Whh,
                            const float* __restrict__ bih, const float* __restrict__ bhh,
                            const float* __restrict__ Wl,  const float* __restrict__ Wr)
{
    int gid = blockIdx.x * 256 + threadIdx.x;
    if (gid < 400 * 64) {
        int frag = gid >> 6, lane = gid & 63;
        int p = frag & 3, kc = (frag >> 2) % 10, qg = frag / 40;
        int row = p * 160 + qg * 16 + (lane & 15);
        int quad = lane >> 4;
        const float* src; int k0;
        if (kc < 5) { src = Wih + row * 160; k0 = kc * 32 + quad * 8; }
        else        { src = Whh + row * 160; k0 = (kc - 5) * 32 + quad * 8; }
        ushort tmp[8];
        #pragma unroll
        for (int j = 0; j < 8; j++) tmp[j] = f2bf(src[k0 + j]);
        ((u32x4*)g_wfrag)[frag * 64 + lane] = *(const u32x4*)tmp;
    } else if (gid < 400 * 64 + 80 * 64) {
        int g2 = gid - 400 * 64;
        int frag = g2 >> 6, lane = g2 & 63;
        int nt = frag & 7, kc = frag >> 3;
        int row = nt * 16 + (lane & 15);
        int quad = lane >> 4;
        int k0 = kc * 32 + quad * 8;
        ushort tmp[8];
        #pragma unroll
        for (int j = 0; j < 8; j++) {
            int k = k0 + j;
            float v = (k < 160) ? Wl[row * 160 + k] : Wr[row * 160 + (k - 160)];
            tmp[j] = f2bf(v);
        }
        ((u32x4*)g_wlrfrag)[frag * 64 + lane] = *(const u32x4*)tmp;
    } else if (gid < 400 * 64 + 80 * 64 + 640) {
        int i = gid - (400 * 64 + 80 * 64);
        g_bsum[i] = bih[i] + bhh[i];
    }
}

// h_in = concat(x, emb[type]) as bf16 rows of 160 (320 B, 16B aligned)
__global__ void build_hin(const float* __restrict__ x, const int* __restrict__ tids,
                          const float* __restrict__ emb)
{
    int i = blockIdx.x * 256 + threadIdx.x;
    if (i >= N_NODES * F_DIM) return;
    int n = i / F_DIM, d = i - n * F_DIM;
    float v = (d < IN_CH) ? x[n * IN_CH + d] : emb[tids[n] * TYPE_DIM + (d - IN_CH)];
    g_hin[i] = f2bf(v);
}

// ---------------------------------------------------------------------------
// R6 = R1 structure (64-node, 10-wave, 1-barrier split pipeline; best 1012us)
// with the two fixes the cycle model demands:
//  * SOFTWARE-PIPELINED WEIGHT STREAM: two 4-frag register buffers (wfA/wfB,
//    32 VGPR), fully unrolled; each kc-group's 4 L2 loads issue one MFMA
//    group ahead of use, and the next epoch's first H-group issues BEFORE
//    the barrier (weight loads have no barrier/LDS dependency). R0-R5 model:
//    per-step time ~= 10 serial load-latency waits; this overlaps them.
//  * NT-GATHER restored (R0-proven): g_hin rows read with nontemporal loads
//    so the streaming gather does not evict the 400KB weight set from L2
//    (R0 FETCH 1.14GB vs R1 2.37GB). Weight loads then hit L2 (~250cyc).
//  * wreg[40] array dropped (spill source: WRITE_SIZE 633MB vs 26MB output).
// Budget: ~100 VGPR + 64 AGPR <= 170 total -> 3 waves/SIMD (10-wave block
// launchable). launch_bounds(640,3) as cap (demand ~= cap; no R2 starvation).
// ---------------------------------------------------------------------------
__launch_bounds__(640, 3)
__global__ void lstm_sage_db(const int* __restrict__ edge_src,
                             const float* __restrict__ bl,
                             float* __restrict__ out)
{
    extern __shared__ ushort lds[];
    constexpr int BSZ  = 64 * LS;
    constexpr int XOFF = 0;            // Xb slots at XOFF + (t&1)*BSZ
    constexpr int HOFF = 2 * BSZ;      // Hb slots at HOFF + (t&1)*BSZ

    const int tid  = threadIdx.x;
    const int lane = tid & 63;
    const int wv   = tid >> 6;           // 0..9 = qg group
    const int col  = lane & 15, quad = lane >> 4;
    const int nb   = blockIdx.x * 64;

    float bG4[4];
    #pragma unroll
    for (int p = 0; p < 4; p++) bG4[p] = g_bsum[p * 160 + wv * 16 + col];

    for (int i = tid; i < BSZ; i += 640) lds[HOFF + i] = 0;   // Hb[0] = h(-1) = 0

    float c_st[4][4];
    #pragma unroll
    for (int m = 0; m < 4; m++)
        #pragma unroll
        for (int r = 0; r < 4; r++) c_st[m][r] = 0.f;

    const int grow  = tid / 10;          // 64 rows x 10 threads
    const int gpart = tid - grow * 10;   // 0..9 -> segs gpart, gpart+10
    const int node_g = nb + grow;
    const int own = (node_g < N_NODES ? node_g : 0);
    const int sbase = own * DEG;

    // prologue: gather X(0) -> slot0, X(1) -> slot1 (NONTEMPORAL: protect L2)
    {
        int s0 = edge_src[sbase + 0];
        int s1 = edge_src[sbase + 1];
        const u32x4* sp0 = (const u32x4*)(g_hin + s0 * F_DIM);
        const u32x4* sp1 = (const u32x4*)(g_hin + s1 * F_DIM);
        u32x4* d0 = (u32x4*)(lds + XOFF + grow * LS);
        u32x4* d1 = (u32x4*)(lds + XOFF + BSZ + grow * LS);
        d0[gpart]      = __builtin_nontemporal_load(sp0 + gpart);
        d0[gpart + 10] = __builtin_nontemporal_load(sp0 + gpart + 10);
        d1[gpart]      = __builtin_nontemporal_load(sp1 + gpart);
        d1[gpart + 10] = __builtin_nontemporal_load(sp1 + gpart + 10);
    }
    int snext = edge_src[sbase + 2];

    const int aoff = col * LS + quad * 8;           // A-frag offset within buffer
    const int hoff = quad * 4 * LS + wv * 16 + col; // h-commit base (row quad*4)
    const u32x4* wq = (const u32x4*)g_wfrag + wv * 40 * 64 + lane;

    // ---- pipelined weight-frag buffers (group G = kc index 0..9, 4 frags) ----
    u32x4 wfA[4], wfB[4];
    f32x4 acc[4][4];

#define ISSUE4(BUF, G) {                       \
    BUF[0] = wq[((G) * 4 + 0) * 64];           \
    BUF[1] = wq[((G) * 4 + 1) * 64];           \
    BUF[2] = wq[((G) * 4 + 2) * 64];           \
    BUF[3] = wq[((G) * 4 + 3) * 64]; }

#define MFMA_GRP(LBASE, KI, BUF) {                                          \
    const ushort* ab_ = (LBASE) + (KI) * 32 + aoff;                         \
    bf16x8 afr_[4];                                                         \
    afr_[0] = *(const bf16x8*)(ab_);                                        \
    afr_[1] = *(const bf16x8*)(ab_ + 16 * LS);                              \
    afr_[2] = *(const bf16x8*)(ab_ + 32 * LS);                              \
    afr_[3] = *(const bf16x8*)(ab_ + 48 * LS);                              \
    _Pragma("unroll")                                                       \
    for (int m_ = 0; m_ < 4; m_++) {                                        \
        _Pragma("unroll")                                                   \
        for (int p_ = 0; p_ < 4; p_++)                                      \
            acc[m_][p_] = __builtin_amdgcn_mfma_f32_16x16x32_bf16(          \
                afr_[m_], *(const bf16x8*)&BUF[p_], acc[m_][p_], 0, 0, 0);  \
    } }

    ISSUE4(wfA, 0);            // X g0 — no barrier dependency
    __syncthreads();           // X(0), X(1), Hb zero visible
    ISSUE4(wfB, 1);

    // acc = bias + X-part(0) on slot 0, pipelined
    #pragma unroll
    for (int m = 0; m < 4; m++)
        #pragma unroll
        for (int p = 0; p < 4; p++)
            acc[m][p] = (f32x4){bG4[p], bG4[p], bG4[p], bG4[p]};
    {
        const ushort* X0 = lds + XOFF;
        MFMA_GRP(X0, 0, wfA);  ISSUE4(wfA, 2);
        MFMA_GRP(X0, 1, wfB);  ISSUE4(wfB, 3);
        MFMA_GRP(X0, 2, wfA);  ISSUE4(wfA, 4);
        MFMA_GRP(X0, 3, wfB);  ISSUE4(wfB, 5);   // H g5 for t=0, crosses barrier
        MFMA_GRP(X0, 4, wfA);
    }

    #pragma unroll 1
    for (int t = 0; t < NSTEP; t++) {
        __syncthreads();   // barrier t: Hb[t&1]=h(t-1), Xb[(t+1)&1]=X(t+1) visible
        const int cur = (t & 1) * BSZ, nxt = ((t & 1) ^ 1) * BSZ;

        // ---- issue gather for X(t+2) (t=14: own row); PARK in regs (nt loads)
        u32x4 P0, P1;
        if (t < NSTEP - 1) {
            const u32x4* sp = (const u32x4*)(g_hin + ((t < NSTEP - 2) ? snext : own) * F_DIM);
            P0 = __builtin_nontemporal_load(sp + gpart);
            P1 = __builtin_nontemporal_load(sp + gpart + 10);
            snext = edge_src[sbase + ((t + 3 < DEG) ? t + 3 : 0)];
        }

        // ---- H-part MFMA: kc 5..9 on Hb[cur]; wfB holds g5 (issued pre-barrier)
        const ushort* Hc = lds + HOFF + cur;
        ISSUE4(wfA, 6);
        MFMA_GRP(Hc, 0, wfB);
        ISSUE4(wfB, 7);
        MFMA_GRP(Hc, 1, wfA);
        ISSUE4(wfA, 8);
        MFMA_GRP(Hc, 2, wfB);
        ISSUE4(wfB, 9);
        MFMA_GRP(Hc, 3, wfA);
        if (t < NSTEP - 1) ISSUE4(wfA, 0);       // X g0 for t+1
        MFMA_GRP(Hc, 4, wfB);

        // ---- elementwise + commit h(t) to Hb[nxt]
        ushort* Hn = lds + HOFF + nxt;
        #pragma unroll
        for (int m = 0; m < 4; m++) {
            #pragma unroll
            for (int r = 0; r < 4; r++) {
                float c = sigmoid_fast(acc[m][1][r]) * c_st[m][r]
                        + sigmoid_fast(acc[m][0][r]) * tanh_fast(acc[m][2][r]);
                c_st[m][r] = c;
                float h = sigmoid_fast(acc[m][3][r]) * tanh_fast(c);
                Hn[hoff + (m * 16 + r) * LS] = f2bf(h);
            }
        }

        if (t < NSTEP - 1) {
            // ---- commit parked gather: X(t+2) -> Xb[t&1]  ((t+2)&1 == t&1)
            {
                u32x4* dp = (u32x4*)(lds + XOFF + cur + grow * LS);
                dp[gpart] = P0; dp[gpart + 10] = P1;
            }
            // ---- PRE-barrier X-part for t+1: kc 0..4 on Xb[(t+1)&1]; wfA = g0
            #pragma unroll
            for (int m = 0; m < 4; m++)
                #pragma unroll
                for (int p = 0; p < 4; p++)
                    acc[m][p] = (f32x4){bG4[p], bG4[p], bG4[p], bG4[p]};
            const ushort* Xn = lds + XOFF + nxt;
            ISSUE4(wfB, 1);
            MFMA_GRP(Xn, 0, wfA);  ISSUE4(wfA, 2);
            MFMA_GRP(Xn, 1, wfB);  ISSUE4(wfB, 3);
            MFMA_GRP(Xn, 2, wfA);  ISSUE4(wfA, 4);
            MFMA_GRP(Xn, 3, wfB);  ISSUE4(wfB, 5);   // H g5 for t+1, crosses barrier
            MFMA_GRP(Xn, 4, wfA);
        }
    }
#undef ISSUE4
#undef MFMA_GRP

    __syncthreads();   // Hb[0]=h(15); Xb[0]=own h_in rows (committed at t=14)

    // out = relu([h_last | h_in] @ [W_l | W_r]^T + b_l)
    // waves 0..7: (m = wv&3, phalf = wv>>2); waves 8,9 idle (no barriers after)
    if (wv < 8) {
        const int m = wv & 3, pb = (wv >> 2) * 4;
        f32x4 acc2[4];
        #pragma unroll
        for (int p = 0; p < 4; p++) {
            float b = bl[(pb + p) * 16 + col];
            acc2[p] = (f32x4){b, b, b, b};
        }
        const u32x4* wq2 = (const u32x4*)g_wlrfrag + lane;
        #pragma unroll
        for (int kc = 0; kc < 10; kc++) {
            bf16x8 bfr[4];
            #pragma unroll
            for (int p = 0; p < 4; p++) {
                u32x4 u = wq2[(kc * 8 + pb + p) * 64];
                bfr[p] = *(const bf16x8*)&u;
            }
            const ushort* ab = ((kc < 5) ? (lds + HOFF + kc * 32) : (lds + XOFF + (kc - 5) * 32))
                               + (m * 16 + col) * LS + quad * 8;
            bf16x8 afr = *(const bf16x8*)ab;
            #pragma unroll
            for (int p = 0; p < 4; p++)
                acc2[p] = __builtin_amdgcn_mfma_f32_16x16x32_bf16(afr, bfr[p], acc2[p], 0, 0, 0);
        }
        #pragma unroll
        for (int p = 0; p < 4; p++) {
            int ocol = (pb + p) * 16 + col;
            #pragma unroll
            for (int r = 0; r < 4; r++) {
                int node = nb + m * 16 + quad * 4 + r;
                if (node < N_NODES) {
                    float v = acc2[p][r];
                    out[node * OUT_CH + ocol] = v > 0.f ? v : 0.f;
                }
            }
        }
    }
}

// ---------------------------------------------------------------------------
// FALLBACK: static 43KB LDS, 2 barriers/step — used only if the dyn-LDS
// attribute probe fails.
// ---------------------------------------------------------------------------
__launch_bounds__(640)
__global__ void lstm_sage_sb(const int* __restrict__ edge_src,
                             const float* __restrict__ bl,
                             float* __restrict__ out)
{
    __shared__ ushort Xb[64 * LS];
    __shared__ ushort Hb[64 * LS];

    const int tid  = threadIdx.x;
    const int lane = tid & 63;
    const int wv   = tid >> 6;
    const int col  = lane & 15, quad = lane >> 4;
    const int nb   = blockIdx.x * 64;

    float bG4[4];
    #pragma unroll
    for (int p = 0; p < 4; p++) bG4[p] = g_bsum[p * 160 + wv * 16 + col];

    for (int i = tid; i < 64 * LS; i += 640) Hb[i] = 0;

    float c_st[4][4];
    #pragma unroll
    for (int m = 0; m < 4; m++)
        #pragma unroll
        for (int r = 0; r < 4; r++) c_st[m][r] = 0.f;

    unsigned hn[4][2];

    const int grow  = tid / 10;
    const int gpart = tid - grow * 10;
    const int node_g = nb + grow;
    const int sbase = (node_g < N_NODES ? node_g : 0) * DEG;

    u32x4 P0, P1;
    {
        int s = edge_src[sbase];
        const u32x4* sp = (const u32x4*)(g_hin + s * F_DIM);
        P0 = __builtin_nontemporal_load(sp + gpart);
        P1 = __builtin_nontemporal_load(sp + gpart + 10);
    }
    int snext = edge_src[sbase + 1];

    #pragma unroll 1
    for (int t = 0; t < NSTEP; t++) {
        if (t > 0) {
            #pragma unroll
            for (int m = 0; m < 4; m++)
                #pragma unroll
                for (int k = 0; k < 2; k++) {
                    int a = (m * 16 + quad * 4 + 2 * k) * LS + wv * 16 + col;
                    unsigned pk = hn[m][k];
                    Hb[a]      = (ushort)pk;
                    Hb[a + LS] = (ushort)(pk >> 16);
                }
        }
        {
            u32x4* dp = (u32x4*)(Xb + grow * LS);
            dp[gpart] = P0; dp[gpart + 10] = P1;
        }
        __syncthreads();

        {
            const u32x4* sp = (t < NSTEP - 1)
                ? (const u32x4*)(g_hin + snext * F_DIM)
                : (const u32x4*)(g_hin + (node_g < N_NODES ? node_g : 0) * F_DIM);
            P0 = __builtin_nontemporal_load(sp + gpart);
            P1 = __builtin_nontemporal_load(sp + gpart + 10);
            snext = edge_src[sbase + ((t + 2 < DEG) ? t + 2 : 0)];
        }

        f32x4 acc[4][4];
        #pragma unroll
        for (int m = 0; m < 4; m++)
            #pragma unroll
            for (int p = 0; p < 4; p++)
                acc[m][p] = (f32x4){bG4[p], bG4[p], bG4[p], bG4[p]};

        const u32x4* wq = (const u32x4*)g_wfrag + wv * 40 * 64 + lane;
        #pragma unroll
        for (int kc = 0; kc < 10; kc++) {
            bf16x8 bfr[4];
            #pragma unroll
            for (int p = 0; p < 4; p++) {
                u32x4 u = wq[(kc * 4 + p) * 64];
                bfr[p] = *(const bf16x8*)&u;
            }
            const ushort* ab = ((kc < 5) ? (Xb + kc * 32) : (Hb + (kc - 5) * 32))
                               + col * LS + quad * 8;
            bf16x8 afr[4];
            #pragma unroll
            for (int m = 0; m < 4; m++)
                afr[m] = *(const bf16x8*)(ab + m * (16 * LS));
            #pragma unroll
            for (int m = 0; m < 4; m++)
                #pragma unroll
                for (int p = 0; p < 4; p++)
                    acc[m][p] = __builtin_amdgcn_mfma_f32_16x16x32_bf16(
                        afr[m], bfr[p], acc[m][p], 0, 0, 0);
        }
        #pragma unroll
        for (int m = 0; m < 4; m++) {
            #pragma unroll
            for (int k = 0; k < 2; k++) {
                unsigned pk = 0;
                #pragma unroll
                for (int h2 = 0; h2 < 2; h2++) {
                    int r = 2 * k + h2;
                    float c = sigmoid_fast(acc[m][1][r]) * c_st[m][r]
                            + sigmoid_fast(acc[m][0][r]) * tanh_fast(acc[m][2][r]);
                    c_st[m][r] = c;
                    float h = sigmoid_fast(acc[m][3][r]) * tanh_fast(c);
                    pk |= ((unsigned)f2bf(h)) << (16 * h2);
                }
                hn[m][k] = pk;
            }
        }
        __syncthreads();
    }

    #pragma unroll
    for (int m = 0; m < 4; m++)
        #pragma unroll
        for (int k = 0; k < 2; k++) {
            int a = (m * 16 + quad * 4 + 2 * k) * LS + wv * 16 + col;
            unsigned pk = hn[m][k];
            Hb[a]      = (ushort)pk;
            Hb[a + LS] = (ushort)(pk >> 16);
        }
    {
        u32x4* dp = (u32x4*)(Xb + grow * LS);
        dp[gpart] = P0; dp[gpart + 10] = P1;
    }
    __syncthreads();

    if (wv < 8) {
        const int m = wv & 3, pb = (wv >> 2) * 4;
        f32x4 acc[4];
        #pragma unroll
        for (int p = 0; p < 4; p++) {
            float b = bl[(pb + p) * 16 + col];
            acc[p] = (f32x4){b, b, b, b};
        }
        const u32x4* wq2 = (const u32x4*)g_wlrfrag + lane;
        #pragma unroll
        for (int kc = 0; kc < 10; kc++) {
            bf16x8 bfr[4];
            #pragma unroll
            for (int p = 0; p < 4; p++) {
                u32x4 u = wq2[(kc * 8 + pb + p) * 64];
                bfr[p] = *(const bf16x8*)&u;
            }
            const ushort* ab = ((kc < 5) ? (Hb + kc * 32) : (Xb + (kc - 5) * 32))
                               + (m * 16 + col) * LS + quad * 8;
            bf16x8 afr = *(const bf16x8*)ab;
            #pragma unroll
            for (int p = 0; p < 4; p++)
                acc[p] = __builtin_amdgcn_mfma_f32_16x16x32_bf16(afr, bfr[p], acc[p], 0, 0, 0);
        }
        #pragma unroll
        for (int p = 0; p < 4; p++) {
            int ocol = (pb + p) * 16 + col;
            #pragma unroll
            for (int r = 0; r < 4; r++) {
                int node = nb + m * 16 + quad * 4 + r;
                if (node < N_NODES) {
                    float v = acc[p][r];
                    out[node * OUT_CH + ocol] = v > 0.f ? v : 0.f;
                }
            }
        }
    }
}

extern "C" void kernel_launch(void* const* d_in, const int* in_sizes, int n_in,
                              void* d_out, int out_size, void* d_ws, size_t ws_size,
                              hipStream_t stream)
{
    const float* x      = (const float*)d_in[0];
    const int*   tids   = (const int*)  d_in[1];
    const int*   esrc   = (const int*)  d_in[2];   // edge_index[0] = src (dst sorted, DEG each)
    const float* emb    = (const float*)d_in[3];
    const float* Wih    = (const float*)d_in[4];
    const float* Whh    = (const float*)d_in[5];
    const float* bih    = (const float*)d_in[6];
    const float* bhh    = (const float*)d_in[7];
    const float* Wl     = (const float*)d_in[8];
    const float* blin   = (const float*)d_in[9];
    const float* Wr     = (const float*)d_in[10];
    float* out = (float*)d_out;

    hipLaunchKernelGGL(pack_kernel, dim3(123), dim3(256), 0, stream,
                       Wih, Whh, bih, bhh, Wl, Wr);
    hipLaunchKernelGGL(build_hin, dim3((N_NODES * F_DIM + 255) / 256), dim3(256), 0, stream,
                       x, tids, emb);

    const int dbShmem = 4 * 64 * LS * (int)sizeof(ushort);   // 86016 B
    (void)hipFuncSetAttribute((const void*)lstm_sage_db,
                              hipFuncAttributeMaxDynamicSharedMemorySize, dbShmem);
    hipFuncAttributes fa;
    bool dbOk = (hipFuncGetAttributes(&fa, (const void*)lstm_sage_db) == hipSuccess) &&
                (fa.maxDynamicSharedSizeBytes >= dbShmem);

    if (dbOk) {
        hipLaunchKernelGGL(lstm_sage_db, dim3((N_NODES + 63) / 64), dim3(640),
                           dbShmem, stream, esrc, blin, out);
    } else {
        hipLaunchKernelGGL(lstm_sage_sb, dim3((N_NODES + 63) / 64), dim3(640),
                           0, stream, esrc, blin, out);
    }
}

// Round 7
// 795.982 us; speedup vs baseline: 2.3205x; 1.5166x over previous
//
#include <hip/hip_runtime.h>
#include <hip/hip_bf16.h>

#define N_NODES 50000
#define DEG     16
#define IN_CH   128
#define TYPE_DIM 32
#define F_DIM   160      // = IN_CH + TYPE_DIM
#define H_DIM   160
#define OUT_CH  128
#define NSTEP   16       // = DEG timesteps
#define LS      168      // LDS row stride in ushorts (16B-aligned)
#define NRES    7        // resident weight frags per wave (kc5 p0-3, kc6 p0-2)

typedef short  bf16x8 __attribute__((ext_vector_type(8)));
typedef float  f32x4  __attribute__((ext_vector_type(4)));
typedef unsigned int u32x4 __attribute__((ext_vector_type(4)));

// Workspace in __device__ globals (cached VRAM) — d_ws is mapped
// uncached/streaming. Fully rewritten every call.
__device__ ushort g_hin[N_NODES * F_DIM];       // 16,000,000 B
__device__ ushort g_wfrag[400 * 64 * 8];        // 409,600 B
__device__ ushort g_wlrfrag[80 * 64 * 8];       // 81,920 B
__device__ float  g_bsum[4 * H_DIM];            // 2,560 B

static __device__ __forceinline__ ushort f2bf(float v) {
    union { float f; unsigned u; } x; x.f = v;
    unsigned r = x.u + 0x7fff + ((x.u >> 16) & 1);   // RNE
    return (ushort)(r >> 16);
}
// v_rcp_f32 (1 instr) instead of IEEE division (~9 instr): R1 proved real win.
static __device__ __forceinline__ float sigmoid_fast(float x) {
    return __builtin_amdgcn_rcpf(1.f + __expf(-x));
}
static __device__ __forceinline__ float tanh_fast(float x) {
    float e = __expf(2.f * x);
    return 1.f - 2.f * __builtin_amdgcn_rcpf(e + 1.f);
}

// ---------------------------------------------------------------------------
// Pack weights into MFMA B-fragment order (bf16), and sum biases.
// Main W frags: frag = qg*40 + kc*4 + p   (qg 0..9, kc 0..9 K-chunk, p gate)
//   kc<5 -> W_ih (X part), kc>=5 -> W_hh (H part)
// Final W frags: frag = kc*8 + nt : row = nt*16+(lane&15), k<160 -> W_l, else W_r
// ---------------------------------------------------------------------------
__global__ void pack_kernel(const float* __restrict__ Wih, const float* __restrict__ Whh,
                            const float* __restrict__ bih, const float* __restrict__ bhh,
                            const float* __restrict__ Wl,  const float* __restrict__ Wr)
{
    int gid = blockIdx.x * 256 + threadIdx.x;
    if (gid < 400 * 64) {
        int frag = gid >> 6, lane = gid & 63;
        int p = frag & 3, kc = (frag >> 2) % 10, qg = frag / 40;
        int row = p * 160 + qg * 16 + (lane & 15);
        int quad = lane >> 4;
        const float* src; int k0;
        if (kc < 5) { src = Wih + row * 160; k0 = kc * 32 + quad * 8; }
        else        { src = Whh + row * 160; k0 = (kc - 5) * 32 + quad * 8; }
        ushort tmp[8];
        #pragma unroll
        for (int j = 0; j < 8; j++) tmp[j] = f2bf(src[k0 + j]);
        ((u32x4*)g_wfrag)[frag * 64 + lane] = *(const u32x4*)tmp;
    } else if (gid < 400 * 64 + 80 * 64) {
        int g2 = gid - 400 * 64;
        int frag = g2 >> 6, lane = g2 & 63;
        int nt = frag & 7, kc = frag >> 3;
        int row = nt * 16 + (lane & 15);
        int quad = lane >> 4;
        int k0 = kc * 32 + quad * 8;
        ushort tmp[8];
        #pragma unroll
        for (int j = 0; j < 8; j++) {
            int k = k0 + j;
            float v = (k < 160) ? Wl[row * 160 + k] : Wr[row * 160 + (k - 160)];
            tmp[j] = f2bf(v);
        }
        ((u32x4*)g_wlrfrag)[frag * 64 + lane] = *(const u32x4*)tmp;
    } else if (gid < 400 * 64 + 80 * 64 + 640) {
        int i = gid - (400 * 64 + 80 * 64);
        g_bsum[i] = bih[i] + bhh[i];
    }
}

// h_in = concat(x, emb[type]) as bf16 rows of 160 (320 B, 16B aligned)
__global__ void build_hin(const float* __restrict__ x, const int* __restrict__ tids,
                          const float* __restrict__ emb)
{
    int i = blockIdx.x * 256 + threadIdx.x;
    if (i >= N_NODES * F_DIM) return;
    int n = i / F_DIM, d = i - n * F_DIM;
    float v = (d < IN_CH) ? x[n * IN_CH + d] : emb[tids[n] * TYPE_DIM + (d - IN_CH)];
    g_hin[i] = f2bf(v);
}

// ---------------------------------------------------------------------------
// R7 = R1-exact base (best measured 1012us: plain gather, in-loop weight
// loads, 84-VGPR codegen, one barrier/step) + LDS-RESIDENT WEIGHT SUBSET.
//
// Session model (fits R1/R4 to ~2%): dur ~= per-CU vector-path bytes /
// ~20 GB/s-per-CU streaming ceiling (m13: HBM copy = 24.6 GB/s/CU). The
// weight re-stream (400KB x 16 steps per block) is 95% of those bytes.
// Fix: 7 of 40 frags/wave (kc5 p0-3 + kc6 p0-2 = 70KB/block) are loaded to
// LDS ONCE per block and ds_read per step. Streamed frags 40 -> 33/step.
// Bonus: the post-barrier critical path (H-part head) now starts from LDS
// (lgkmcnt ~120cyc, no vmcnt ordering vs the gather) not global loads.
// LDS: 86016 (X/H dbuf) + 71680 (resident) = 157696 <= 160KB.
// ---------------------------------------------------------------------------
__launch_bounds__(640, 3)
__global__ void lstm_sage_db(const int* __restrict__ edge_src,
                             const float* __restrict__ bl,
                             float* __restrict__ out)
{
    extern __shared__ ushort lds[];
    constexpr int BSZ  = 64 * LS;
    constexpr int XOFF = 0;            // Xb slots at XOFF + (t&1)*BSZ
    constexpr int HOFF = 2 * BSZ;      // Hb slots at HOFF + (t&1)*BSZ
    constexpr int WOFF = 4 * BSZ;      // resident weights: 7 frags x 10 waves

    const int tid  = threadIdx.x;
    const int lane = tid & 63;
    const int wv   = tid >> 6;           // 0..9 = qg group
    const int col  = lane & 15, quad = lane >> 4;
    const int nb   = blockIdx.x * 64;

    float bG4[4];
    #pragma unroll
    for (int p = 0; p < 4; p++) bG4[p] = g_bsum[p * 160 + wv * 16 + col];

    for (int i = tid; i < BSZ; i += 640) lds[HOFF + i] = 0;   // Hb[0] = h(-1) = 0

    float c_st[4][4];
    #pragma unroll
    for (int m = 0; m < 4; m++)
        #pragma unroll
        for (int r = 0; r < 4; r++) c_st[m][r] = 0.f;

    const int grow  = tid / 10;          // 64 rows x 10 threads
    const int gpart = tid - grow * 10;   // 0..9 -> segs gpart, gpart+10
    const int node_g = nb + grow;
    const int own = (node_g < N_NODES ? node_g : 0);
    const int sbase = own * DEG;

    const u32x4* wq = (const u32x4*)g_wfrag + wv * 40 * 64 + lane;

    // ---- resident weight load: once per block, frags f0..3=kc5 p0..3,
    //      f4..6=kc6 p0..2.  Layout: (wv*7+f)*64 + lane  (u32x4 units).
    {
        u32x4* wl = (u32x4*)(lds + WOFF) + wv * (NRES * 64) + lane;
        #pragma unroll
        for (int f = 0; f < NRES; f++) {
            int kcp = (f < 4) ? (5 * 4 + f) : (6 * 4 + (f - 4));
            wl[f * 64] = wq[kcp * 64];
        }
    }
    const u32x4* wlr = (const u32x4*)(lds + WOFF) + wv * (NRES * 64) + lane;

    // prologue: gather X(0) -> slot0, X(1) -> slot1 (plain cacheable loads)
    {
        int s0 = edge_src[sbase + 0];
        int s1 = edge_src[sbase + 1];
        const u32x4* sp0 = (const u32x4*)(g_hin + s0 * F_DIM);
        const u32x4* sp1 = (const u32x4*)(g_hin + s1 * F_DIM);
        u32x4* d0 = (u32x4*)(lds + XOFF + grow * LS);
        u32x4* d1 = (u32x4*)(lds + XOFF + BSZ + grow * LS);
        d0[gpart]      = sp0[gpart];
        d0[gpart + 10] = sp0[gpart + 10];
        d1[gpart]      = sp1[gpart];
        d1[gpart + 10] = sp1[gpart + 10];
    }
    int snext = edge_src[sbase + 2];

    const int aoff = col * LS + quad * 8;           // A-frag offset within buffer
    const int hoff = quad * 4 * LS + wv * 16 + col; // h-commit base (row quad*4)

    __syncthreads();   // X(0), X(1), Hb zero, resident weights visible

    // acc = bias + X-part(0)  (slot 0, streamed weights like R1)
    f32x4 acc[4][4];
    #pragma unroll
    for (int m = 0; m < 4; m++)
        #pragma unroll
        for (int p = 0; p < 4; p++)
            acc[m][p] = (f32x4){bG4[p], bG4[p], bG4[p], bG4[p]};
    #pragma unroll
    for (int kx = 0; kx < 5; kx++) {
        bf16x8 bfr[4];
        #pragma unroll
        for (int p = 0; p < 4; p++) {
            u32x4 u = wq[(kx * 4 + p) * 64];
            bfr[p] = *(const bf16x8*)&u;
        }
        const ushort* ab = lds + XOFF + kx * 32 + aoff;   // slot 0
        bf16x8 afr[4];
        #pragma unroll
        for (int m = 0; m < 4; m++)
            afr[m] = *(const bf16x8*)(ab + m * (16 * LS));
        #pragma unroll
        for (int m = 0; m < 4; m++)
            #pragma unroll
            for (int p = 0; p < 4; p++)
                acc[m][p] = __builtin_amdgcn_mfma_f32_16x16x32_bf16(
                    afr[m], bfr[p], acc[m][p], 0, 0, 0);
    }

    #pragma unroll 1
    for (int t = 0; t < NSTEP; t++) {
        __syncthreads();   // barrier t: Hb[t&1]=h(t-1), Xb[(t+1)&1]=X(t+1) visible
        const int cur = (t & 1) * BSZ, nxt = ((t & 1) ^ 1) * BSZ;

        // ---- issue gather for X(t+2) (t=14: own row); PARK in regs
        u32x4 P0, P1;
        if (t < NSTEP - 1) {
            const u32x4* sp = (const u32x4*)(g_hin + ((t < NSTEP - 2) ? snext : own) * F_DIM);
            P0 = sp[gpart];
            P1 = sp[gpart + 10];
            snext = edge_src[sbase + ((t + 3 < DEG) ? t + 3 : 0)];
        }

        // ---- H-part MFMA: kc 5..9 on Hb[cur]
        //      kh=0 (kc5): all 4 bfr from LDS-resident
        //      kh=1 (kc6): p0..2 resident, p3 streamed
        //      kh=2..4   : streamed (R1 in-loop pattern)
        const ushort* Hc = lds + HOFF + cur;
        #pragma unroll
        for (int kh = 0; kh < 5; kh++) {
            bf16x8 bfr[4];
            #pragma unroll
            for (int p = 0; p < 4; p++) {
                u32x4 u;
                if (kh == 0)                u = wlr[p * 64];               // f=p
                else if (kh == 1 && p < 3)  u = wlr[(4 + p) * 64];         // f=4+p
                else                        u = wq[((5 + kh) * 4 + p) * 64];
                bfr[p] = *(const bf16x8*)&u;
            }
            const ushort* ab = Hc + kh * 32 + aoff;
            bf16x8 afr[4];
            #pragma unroll
            for (int m = 0; m < 4; m++)
                afr[m] = *(const bf16x8*)(ab + m * (16 * LS));
            #pragma unroll
            for (int m = 0; m < 4; m++)
                #pragma unroll
                for (int p = 0; p < 4; p++)
                    acc[m][p] = __builtin_amdgcn_mfma_f32_16x16x32_bf16(
                        afr[m], bfr[p], acc[m][p], 0, 0, 0);
        }

        // ---- elementwise + commit h(t) to Hb[nxt]
        ushort* Hn = lds + HOFF + nxt;
        #pragma unroll
        for (int m = 0; m < 4; m++) {
            #pragma unroll
            for (int r = 0; r < 4; r++) {
                float c = sigmoid_fast(acc[m][1][r]) * c_st[m][r]
                        + sigmoid_fast(acc[m][0][r]) * tanh_fast(acc[m][2][r]);
                c_st[m][r] = c;
                float h = sigmoid_fast(acc[m][3][r]) * tanh_fast(c);
                Hn[hoff + (m * 16 + r) * LS] = f2bf(h);
            }
        }

        if (t < NSTEP - 1) {
            // ---- commit parked gather: X(t+2) -> Xb[t&1]  ((t+2)&1 == t&1)
            {
                u32x4* dp = (u32x4*)(lds + XOFF + cur + grow * LS);
                dp[gpart] = P0; dp[gpart + 10] = P1;
            }
            // ---- PRE-barrier X-part for t+1: kc 0..4 on Xb[(t+1)&1]
            #pragma unroll
            for (int m = 0; m < 4; m++)
                #pragma unroll
                for (int p = 0; p < 4; p++)
                    acc[m][p] = (f32x4){bG4[p], bG4[p], bG4[p], bG4[p]};
            const ushort* Xn = lds + XOFF + nxt;
            #pragma unroll
            for (int kx = 0; kx < 5; kx++) {
                bf16x8 bfr[4];
                #pragma unroll
                for (int p = 0; p < 4; p++) {
                    u32x4 u = wq[(kx * 4 + p) * 64];
                    bfr[p] = *(const bf16x8*)&u;
                }
                const ushort* ab = Xn + kx * 32 + aoff;
                bf16x8 afr[4];
                #pragma unroll
                for (int m = 0; m < 4; m++)
                    afr[m] = *(const bf16x8*)(ab + m * (16 * LS));
                #pragma unroll
                for (int m = 0; m < 4; m++)
                    #pragma unroll
                    for (int p = 0; p < 4; p++)
                        acc[m][p] = __builtin_amdgcn_mfma_f32_16x16x32_bf16(
                            afr[m], bfr[p], acc[m][p], 0, 0, 0);
            }
        }
    }

    __syncthreads();   // Hb[0]=h(15); Xb[0]=own h_in rows (committed at t=14)

    // out = relu([h_last | h_in] @ [W_l | W_r]^T + b_l)
    // waves 0..7: (m = wv&3, phalf = wv>>2); waves 8,9 idle (no barriers after)
    if (wv < 8) {
        const int m = wv & 3, pb = (wv >> 2) * 4;
        f32x4 acc2[4];
        #pragma unroll
        for (int p = 0; p < 4; p++) {
            float b = bl[(pb + p) * 16 + col];
            acc2[p] = (f32x4){b, b, b, b};
        }
        const u32x4* wq2 = (const u32x4*)g_wlrfrag + lane;
        #pragma unroll
        for (int kc = 0; kc < 10; kc++) {
            bf16x8 bfr[4];
            #pragma unroll
            for (int p = 0; p < 4; p++) {
                u32x4 u = wq2[(kc * 8 + pb + p) * 64];
                bfr[p] = *(const bf16x8*)&u;
            }
            const ushort* ab = ((kc < 5) ? (lds + HOFF + kc * 32) : (lds + XOFF + (kc - 5) * 32))
                               + (m * 16 + col) * LS + quad * 8;
            bf16x8 afr = *(const bf16x8*)ab;
            #pragma unroll
            for (int p = 0; p < 4; p++)
                acc2[p] = __builtin_amdgcn_mfma_f32_16x16x32_bf16(afr, bfr[p], acc2[p], 0, 0, 0);
        }
        #pragma unroll
        for (int p = 0; p < 4; p++) {
            int ocol = (pb + p) * 16 + col;
            #pragma unroll
            for (int r = 0; r < 4; r++) {
                int node = nb + m * 16 + quad * 4 + r;
                if (node < N_NODES) {
                    float v = acc2[p][r];
                    out[node * OUT_CH + ocol] = v > 0.f ? v : 0.f;
                }
            }
        }
    }
}

// ---------------------------------------------------------------------------
// FALLBACK: static 43KB LDS, 2 barriers/step — used only if the dyn-LDS
// attribute probe fails.
// ---------------------------------------------------------------------------
__launch_bounds__(640)
__global__ void lstm_sage_sb(const int* __restrict__ edge_src,
                             const float* __restrict__ bl,
                             float* __restrict__ out)
{
    __shared__ ushort Xb[64 * LS];
    __shared__ ushort Hb[64 * LS];

    const int tid  = threadIdx.x;
    const int lane = tid & 63;
    const int wv   = tid >> 6;
    const int col  = lane & 15, quad = lane >> 4;
    const int nb   = blockIdx.x * 64;

    float bG4[4];
    #pragma unroll
    for (int p = 0; p < 4; p++) bG4[p] = g_bsum[p * 160 + wv * 16 + col];

    for (int i = tid; i < 64 * LS; i += 640) Hb[i] = 0;

    float c_st[4][4];
    #pragma unroll
    for (int m = 0; m < 4; m++)
        #pragma unroll
        for (int r = 0; r < 4; r++) c_st[m][r] = 0.f;

    unsigned hn[4][2];

    const int grow  = tid / 10;
    const int gpart = tid - grow * 10;
    const int node_g = nb + grow;
    const int sbase = (node_g < N_NODES ? node_g : 0) * DEG;

    u32x4 P0, P1;
    {
        int s = edge_src[sbase];
        const u32x4* sp = (const u32x4*)(g_hin + s * F_DIM);
        P0 = sp[gpart]; P1 = sp[gpart + 10];
    }
    int snext = edge_src[sbase + 1];

    #pragma unroll 1
    for (int t = 0; t < NSTEP; t++) {
        if (t > 0) {
            #pragma unroll
            for (int m = 0; m < 4; m++)
                #pragma unroll
                for (int k = 0; k < 2; k++) {
                    int a = (m * 16 + quad * 4 + 2 * k) * LS + wv * 16 + col;
                    unsigned pk = hn[m][k];
                    Hb[a]      = (ushort)pk;
                    Hb[a + LS] = (ushort)(pk >> 16);
                }
        }
        {
            u32x4* dp = (u32x4*)(Xb + grow * LS);
            dp[gpart] = P0; dp[gpart + 10] = P1;
        }
        __syncthreads();

        {
            const u32x4* sp = (t < NSTEP - 1)
                ? (const u32x4*)(g_hin + snext * F_DIM)
                : (const u32x4*)(g_hin + (node_g < N_NODES ? node_g : 0) * F_DIM);
            P0 = sp[gpart]; P1 = sp[gpart + 10];
            snext = edge_src[sbase + ((t + 2 < DEG) ? t + 2 : 0)];
        }

        f32x4 acc[4][4];
        #pragma unroll
        for (int m = 0; m < 4; m++)
            #pragma unroll
            for (int p = 0; p < 4; p++)
                acc[m][p] = (f32x4){bG4[p], bG4[p], bG4[p], bG4[p]};

        const u32x4* wq = (const u32x4*)g_wfrag + wv * 40 * 64 + lane;
        #pragma unroll
        for (int kc = 0; kc < 10; kc++) {
            bf16x8 bfr[4];
            #pragma unroll
            for (int p = 0; p < 4; p++) {
                u32x4 u = wq[(kc * 4 + p) * 64];
                bfr[p] = *(const bf16x8*)&u;
            }
            const ushort* ab = ((kc < 5) ? (Xb + kc * 32) : (Hb + (kc - 5) * 32))
                               + col * LS + quad * 8;
            bf16x8 afr[4];
            #pragma unroll
            for (int m = 0; m < 4; m++)
                afr[m] = *(const bf16x8*)(ab + m * (16 * LS));
            #pragma unroll
            for (int m = 0; m < 4; m++)
                #pragma unroll
                for (int p = 0; p < 4; p++)
                    acc[m][p] = __builtin_amdgcn_mfma_f32_16x16x32_bf16(
                        afr[m], bfr[p], acc[m][p], 0, 0, 0);
        }
        #pragma unroll
        for (int m = 0; m < 4; m++) {
            #pragma unroll
            for (int k = 0; k < 2; k++) {
                unsigned pk = 0;
                #pragma unroll
                for (int h2 = 0; h2 < 2; h2++) {
                    int r = 2 * k + h2;
                    float c = sigmoid_fast(acc[m][1][r]) * c_st[m][r]
                            + sigmoid_fast(acc[m][0][r]) * tanh_fast(acc[m][2][r]);
                    c_st[m][r] = c;
                    float h = sigmoid_fast(acc[m][3][r]) * tanh_fast(c);
                    pk |= ((unsigned)f2bf(h)) << (16 * h2);
                }
                hn[m][k] = pk;
            }
        }
        __syncthreads();
    }

    #pragma unroll
    for (int m = 0; m < 4; m++)
        #pragma unroll
        for (int k = 0; k < 2; k++) {
            int a = (m * 16 + quad * 4 + 2 * k) * LS + wv * 16 + col;
            unsigned pk = hn[m][k];
            Hb[a]      = (ushort)pk;
            Hb[a + LS] = (ushort)(pk >> 16);
        }
    {
        u32x4* dp = (u32x4*)(Xb + grow * LS);
        dp[gpart] = P0; dp[gpart + 10] = P1;
    }
    __syncthreads();

    if (wv < 8) {
        const int m = wv & 3, pb = (wv >> 2) * 4;
        f32x4 acc[4];
        #pragma unroll
        for (int p = 0; p < 4; p++) {
            float b = bl[(pb + p) * 16 + col];
            acc[p] = (f32x4){b, b, b, b};
        }
        const u32x4* wq2 = (const u32x4*)g_wlrfrag + lane;
        #pragma unroll
        for (int kc = 0; kc < 10; kc++) {
            bf16x8 bfr[4];
            #pragma unroll
            for (int p = 0; p < 4; p++) {
                u32x4 u = wq2[(kc * 8 + pb + p) * 64];
                bfr[p] = *(const bf16x8*)&u;
            }
            const ushort* ab = ((kc < 5) ? (Hb + kc * 32) : (Xb + (kc - 5) * 32))
                               + (m * 16 + col) * LS + quad * 8;
            bf16x8 afr = *(const bf16x8*)ab;
            #pragma unroll
            for (int p = 0; p < 4; p++)
                acc[p] = __builtin_amdgcn_mfma_f32_16x16x32_bf16(afr, bfr[p], acc[p], 0, 0, 0);
        }
        #pragma unroll
        for (int p = 0; p < 4; p++) {
            int ocol = (pb + p) * 16 + col;
            #pragma unroll
            for (int r = 0; r < 4; r++) {
                int node = nb + m * 16 + quad * 4 + r;
                if (node < N_NODES) {
                    float v = acc[p][r];
                    out[node * OUT_CH + ocol] = v > 0.f ? v : 0.f;
                }
            }
        }
    }
}

extern "C" void kernel_launch(void* const* d_in, const int* in_sizes, int n_in,
                              void* d_out, int out_size, void* d_ws, size_t ws_size,
                              hipStream_t stream)
{
    const float* x      = (const float*)d_in[0];
    const int*   tids   = (const int*)  d_in[1];
    const int*   esrc   = (const int*)  d_in[2];   // edge_index[0] = src (dst sorted, DEG each)
    const float* emb    = (const float*)d_in[3];
    const float* Wih    = (const float*)d_in[4];
    const float* Whh    = (const float*)d_in[5];
    const float* bih    = (const float*)d_in[6];
    const float* bhh    = (const float*)d_in[7];
    const float* Wl     = (const float*)d_in[8];
    const float* blin   = (const float*)d_in[9];
    const float* Wr     = (const float*)d_in[10];
    float* out = (float*)d_out;

    hipLaunchKernelGGL(pack_kernel, dim3(123), dim3(256), 0, stream,
                       Wih, Whh, bih, bhh, Wl, Wr);
    hipLaunchKernelGGL(build_hin, dim3((N_NODES * F_DIM + 255) / 256), dim3(256), 0, stream,
                       x, tids, emb);

    // 86016 (X/H dbuf) + 71680 (resident weights) = 157696 B
    const int dbShmem = (4 * 64 * LS + NRES * 10 * 64 * 8) * (int)sizeof(ushort);
    (void)hipFuncSetAttribute((const void*)lstm_sage_db,
                              hipFuncAttributeMaxDynamicSharedMemorySize, dbShmem);
    hipFuncAttributes fa;
    bool dbOk = (hipFuncGetAttributes(&fa, (const void*)lstm_sage_db) == hipSuccess) &&
                (fa.maxDynamicSharedSizeBytes >= dbShmem);

    if (dbOk) {
        hipLaunchKernelGGL(lstm_sage_db, dim3((N_NODES + 63) / 64), dim3(640),
                           dbShmem, stream, esrc, blin, out);
    } else {
        hipLaunchKernelGGL(lstm_sage_sb, dim3((N_NODES + 63) / 64), dim3(640),
                           0, stream, esrc, blin, out);
    }
}

// Round 8
// 737.507 us; speedup vs baseline: 2.5045x; 1.0793x over previous
//
#include <hip/hip_runtime.h>
#include <hip/hip_bf16.h>

#define N_NODES 50000
#define DEG     16
#define IN_CH   128
#define TYPE_DIM 32
#define F_DIM   160      // = IN_CH + TYPE_DIM
#define H_DIM   160
#define OUT_CH  128
#define NSTEP   16       // = DEG timesteps
#define LS      168      // LDS row stride in ushorts (16B-aligned)
#define NRES    11       // resident frags/wave: kc5 p0-3, kc6 p0-3, kc7 p0-2

typedef short  bf16x8 __attribute__((ext_vector_type(8)));
typedef float  f32x4  __attribute__((ext_vector_type(4)));
typedef unsigned int u32x4 __attribute__((ext_vector_type(4)));

// Workspace in __device__ globals (cached VRAM) — d_ws is mapped
// uncached/streaming. Fully rewritten every call.
__device__ ushort g_hin[N_NODES * F_DIM];       // 16,000,000 B
__device__ ushort g_wfrag[400 * 64 * 8];        // 409,600 B
__device__ ushort g_wlrfrag[80 * 64 * 8];       // 81,920 B
__device__ float  g_bsum[4 * H_DIM];            // 2,560 B

static __device__ __forceinline__ ushort f2bf(float v) {
    union { float f; unsigned u; } x; x.f = v;
    unsigned r = x.u + 0x7fff + ((x.u >> 16) & 1);   // RNE
    return (ushort)(r >> 16);
}
// v_rcp_f32 (1 instr) instead of IEEE division (~9 instr): R1 proved real win.
static __device__ __forceinline__ float sigmoid_fast(float x) {
    return __builtin_amdgcn_rcpf(1.f + __expf(-x));
}
static __device__ __forceinline__ float tanh_fast(float x) {
    float e = __expf(2.f * x);
    return 1.f - 2.f * __builtin_amdgcn_rcpf(e + 1.f);
}

// ---------------------------------------------------------------------------
// Pack weights into MFMA B-fragment order (bf16), and sum biases.
// Main W frags: frag = qg*40 + kc*4 + p   (qg 0..9, kc 0..9 K-chunk, p gate)
//   kc<5 -> W_ih (X part), kc>=5 -> W_hh (H part)
// Final W frags: frag = kc*8 + nt : row = nt*16+(lane&15), k<160 -> W_l, else W_r
// ---------------------------------------------------------------------------
__global__ void pack_kernel(const float* __restrict__ Wih, const float* __restrict__ Whh,
                            const float* __restrict__ bih, const float* __restrict__ bhh,
                            const float* __restrict__ Wl,  const float* __restrict__ Wr)
{
    int gid = blockIdx.x * 256 + threadIdx.x;
    if (gid < 400 * 64) {
        int frag = gid >> 6, lane = gid & 63;
        int p = frag & 3, kc = (frag >> 2) % 10, qg = frag / 40;
        int row = p * 160 + qg * 16 + (lane & 15);
        int quad = lane >> 4;
        const float* src; int k0;
        if (kc < 5) { src = Wih + row * 160; k0 = kc * 32 + quad * 8; }
        else        { src = Whh + row * 160; k0 = (kc - 5) * 32 + quad * 8; }
        ushort tmp[8];
        #pragma unroll
        for (int j = 0; j < 8; j++) tmp[j] = f2bf(src[k0 + j]);
        ((u32x4*)g_wfrag)[frag * 64 + lane] = *(const u32x4*)tmp;
    } else if (gid < 400 * 64 + 80 * 64) {
        int g2 = gid - 400 * 64;
        int frag = g2 >> 6, lane = g2 & 63;
        int nt = frag & 7, kc = frag >> 3;
        int row = nt * 16 + (lane & 15);
        int quad = lane >> 4;
        int k0 = kc * 32 + quad * 8;
        ushort tmp[8];
        #pragma unroll
        for (int j = 0; j < 8; j++) {
            int k = k0 + j;
            float v = (k < 160) ? Wl[row * 160 + k] : Wr[row * 160 + (k - 160)];
            tmp[j] = f2bf(v);
        }
        ((u32x4*)g_wlrfrag)[frag * 64 + lane] = *(const u32x4*)tmp;
    } else if (gid < 400 * 64 + 80 * 64 + 640) {
        int i = gid - (400 * 64 + 80 * 64);
        g_bsum[i] = bih[i] + bhh[i];
    }
}

// h_in = concat(x, emb[type]) as bf16 rows of 160 (320 B, 16B aligned)
__global__ void build_hin(const float* __restrict__ x, const int* __restrict__ tids,
                          const float* __restrict__ emb)
{
    int i = blockIdx.x * 256 + threadIdx.x;
    if (i >= N_NODES * F_DIM) return;
    int n = i / F_DIM, d = i - n * F_DIM;
    float v = (d < IN_CH) ? x[n * IN_CH + d] : emb[tids[n] * TYPE_DIM + (d - IN_CH)];
    g_hin[i] = f2bf(v);
}

// ---------------------------------------------------------------------------
// R8 = R7's winning lever (LDS-resident weights) extended to the LDS budget
// limit via the single-buffer sb layout (2 barriers/step, 43KB X/H):
//   resident frags/wave 7 -> 11 (kc5 p0-3, kc6 p0-3, kc7 p0-2 = 112.6KB).
//   streamed frags/step 33 -> 29 (-12% of the binding vmem byte stream).
// R7 confirmed the model: dur ~ streamed-weight bytes through the per-CU
// vector path (~23 GB/s/CU effective); FETCH collapsed 2.37GB->575MB and
// dur 1012->750 when 7 frags went resident. The H-part head (kc5-7) now
// has ZERO vmem dependency after the barrier.
// LDS: 2*21504 (Xb,Hb) + 112640 (resident) = 155648 <= 160KB (dynamic).
// Gather stays plain cacheable (R7-proven; nt regressed in R0/R6).
// ---------------------------------------------------------------------------
__launch_bounds__(640, 3)
__global__ void lstm_sage_r11(const int* __restrict__ edge_src,
                              const float* __restrict__ bl,
                              float* __restrict__ out)
{
    extern __shared__ ushort lds[];
    constexpr int BSZ  = 64 * LS;      // 10752 ushorts = 21504 B
    constexpr int XOFF = 0;            // Xb (single buffer)
    constexpr int HOFF = BSZ;          // Hb (single buffer)
    constexpr int WOFF = 2 * BSZ;      // resident weights: 11 frags x 10 waves

    const int tid  = threadIdx.x;
    const int lane = tid & 63;
    const int wv   = tid >> 6;           // 0..9 = qg group
    const int col  = lane & 15, quad = lane >> 4;
    const int nb   = blockIdx.x * 64;

    float bG4[4];
    #pragma unroll
    for (int p = 0; p < 4; p++) bG4[p] = g_bsum[p * 160 + wv * 16 + col];

    for (int i = tid; i < BSZ; i += 640) lds[HOFF + i] = 0;   // h(-1) = 0

    float c_st[4][4];
    #pragma unroll
    for (int m = 0; m < 4; m++)
        #pragma unroll
        for (int r = 0; r < 4; r++) c_st[m][r] = 0.f;

    unsigned hn[4][2];                   // h(t) staging regs (packed bf16 pairs)

    const int grow  = tid / 10;          // 64 rows x 10 threads
    const int gpart = tid - grow * 10;   // 0..9 -> segs gpart, gpart+10
    const int node_g = nb + grow;
    const int own = (node_g < N_NODES ? node_g : 0);
    const int sbase = own * DEG;

    const u32x4* wq = (const u32x4*)g_wfrag + wv * 40 * 64 + lane;

    // ---- resident weight load: once per block.
    //      f0..3 = kc5 p0..3, f4..7 = kc6 p0..3, f8..10 = kc7 p0..2.
    //      Layout: (wv*NRES+f)*64 + lane (u32x4 units). Wave-private region.
    {
        u32x4* wl = (u32x4*)(lds + WOFF) + wv * (NRES * 64) + lane;
        #pragma unroll
        for (int f = 0; f < NRES; f++) {
            int kcp = (f < 8) ? (5 * 4 + f) : (7 * 4 + (f - 8));
            wl[f * 64] = wq[kcp * 64];
        }
    }
    const u32x4* wlr = (const u32x4*)(lds + WOFF) + wv * (NRES * 64) + lane;

    // prologue: park X(0) (plain cacheable loads; ~16x reuse per g_hin row)
    u32x4 P0, P1;
    {
        int s = edge_src[sbase];
        const u32x4* sp = (const u32x4*)(g_hin + s * F_DIM);
        P0 = sp[gpart]; P1 = sp[gpart + 10];
    }
    int snext = edge_src[sbase + 1];

    const int aoff = col * LS + quad * 8;           // A-frag offset within buffer

    #pragma unroll 1
    for (int t = 0; t < NSTEP; t++) {
        // ---- commit h(t-1) regs and parked X(t) to LDS (pre-barrier window)
        if (t > 0) {
            #pragma unroll
            for (int m = 0; m < 4; m++)
                #pragma unroll
                for (int k = 0; k < 2; k++) {
                    int a = (m * 16 + quad * 4 + 2 * k) * LS + wv * 16 + col;
                    unsigned pk = hn[m][k];
                    lds[HOFF + a]      = (ushort)pk;
                    lds[HOFF + a + LS] = (ushort)(pk >> 16);
                }
        }
        {
            u32x4* dp = (u32x4*)(lds + XOFF + grow * LS);
            dp[gpart] = P0; dp[gpart + 10] = P1;
        }
        __syncthreads();

        // ---- park next gather (t=15: own h_in row for the epilogue)
        {
            const u32x4* sp = (t < NSTEP - 1)
                ? (const u32x4*)(g_hin + snext * F_DIM)
                : (const u32x4*)(g_hin + own * F_DIM);
            P0 = sp[gpart]; P1 = sp[gpart + 10];
            snext = edge_src[sbase + ((t + 2 < DEG) ? t + 2 : 0)];
        }

        f32x4 acc[4][4];
        #pragma unroll
        for (int m = 0; m < 4; m++)
            #pragma unroll
            for (int p = 0; p < 4; p++)
                acc[m][p] = (f32x4){bG4[p], bG4[p], bG4[p], bG4[p]};

        // ---- kc loop: kc5/kc6 fully + kc7 p0-2 from LDS-resident; rest streamed
        #pragma unroll
        for (int kc = 0; kc < 10; kc++) {
            bf16x8 bfr[4];
            #pragma unroll
            for (int p = 0; p < 4; p++) {
                u32x4 u;
                if (kc == 5)               u = wlr[p * 64];
                else if (kc == 6)          u = wlr[(4 + p) * 64];
                else if (kc == 7 && p < 3) u = wlr[(8 + p) * 64];
                else                       u = wq[(kc * 4 + p) * 64];
                bfr[p] = *(const bf16x8*)&u;
            }
            const ushort* ab = ((kc < 5) ? (lds + XOFF + kc * 32)
                                         : (lds + HOFF + (kc - 5) * 32)) + aoff;
            bf16x8 afr[4];
            #pragma unroll
            for (int m = 0; m < 4; m++)
                afr[m] = *(const bf16x8*)(ab + m * (16 * LS));
            #pragma unroll
            for (int m = 0; m < 4; m++)
                #pragma unroll
                for (int p = 0; p < 4; p++)
                    acc[m][p] = __builtin_amdgcn_mfma_f32_16x16x32_bf16(
                        afr[m], bfr[p], acc[m][p], 0, 0, 0);
        }

        // ---- elementwise -> h(t) staged in regs (committed next loop top)
        #pragma unroll
        for (int m = 0; m < 4; m++) {
            #pragma unroll
            for (int k = 0; k < 2; k++) {
                unsigned pk = 0;
                #pragma unroll
                for (int h2 = 0; h2 < 2; h2++) {
                    int r = 2 * k + h2;
                    float c = sigmoid_fast(acc[m][1][r]) * c_st[m][r]
                            + sigmoid_fast(acc[m][0][r]) * tanh_fast(acc[m][2][r]);
                    c_st[m][r] = c;
                    float h = sigmoid_fast(acc[m][3][r]) * tanh_fast(c);
                    pk |= ((unsigned)f2bf(h)) << (16 * h2);
                }
                hn[m][k] = pk;
            }
        }
        __syncthreads();
    }

    // ---- final commit: Hb = h(15), Xb = own h_in rows (parked at t=15)
    #pragma unroll
    for (int m = 0; m < 4; m++)
        #pragma unroll
        for (int k = 0; k < 2; k++) {
            int a = (m * 16 + quad * 4 + 2 * k) * LS + wv * 16 + col;
            unsigned pk = hn[m][k];
            lds[HOFF + a]      = (ushort)pk;
            lds[HOFF + a + LS] = (ushort)(pk >> 16);
        }
    {
        u32x4* dp = (u32x4*)(lds + XOFF + grow * LS);
        dp[gpart] = P0; dp[gpart + 10] = P1;
    }
    __syncthreads();

    // ---- out = relu([h_last | h_in] @ [W_l | W_r]^T + b_l)
    // waves 0..7: (m = wv&3, phalf = wv>>2); waves 8,9 idle (no barriers after)
    if (wv < 8) {
        const int m = wv & 3, pb = (wv >> 2) * 4;
        f32x4 acc2[4];
        #pragma unroll
        for (int p = 0; p < 4; p++) {
            float b = bl[(pb + p) * 16 + col];
            acc2[p] = (f32x4){b, b, b, b};
        }
        const u32x4* wq2 = (const u32x4*)g_wlrfrag + lane;
        #pragma unroll
        for (int kc = 0; kc < 10; kc++) {
            bf16x8 bfr[4];
            #pragma unroll
            for (int p = 0; p < 4; p++) {
                u32x4 u = wq2[(kc * 8 + pb + p) * 64];
                bfr[p] = *(const bf16x8*)&u;
            }
            const ushort* ab = ((kc < 5) ? (lds + HOFF + kc * 32)
                                         : (lds + XOFF + (kc - 5) * 32))
                               + (m * 16 + col) * LS + quad * 8;
            bf16x8 afr = *(const bf16x8*)ab;
            #pragma unroll
            for (int p = 0; p < 4; p++)
                acc2[p] = __builtin_amdgcn_mfma_f32_16x16x32_bf16(afr, bfr[p], acc2[p], 0, 0, 0);
        }
        #pragma unroll
        for (int p = 0; p < 4; p++) {
            int ocol = (pb + p) * 16 + col;
            #pragma unroll
            for (int r = 0; r < 4; r++) {
                int node = nb + m * 16 + quad * 4 + r;
                if (node < N_NODES) {
                    float v = acc2[p][r];
                    out[node * OUT_CH + ocol] = v > 0.f ? v : 0.f;
                }
            }
        }
    }
}

// ---------------------------------------------------------------------------
// FALLBACK: static 43KB LDS, 2 barriers/step, all weights streamed — used
// only if the dynamic-LDS attribute probe fails.
// ---------------------------------------------------------------------------
__launch_bounds__(640)
__global__ void lstm_sage_sb(const int* __restrict__ edge_src,
                             const float* __restrict__ bl,
                             float* __restrict__ out)
{
    __shared__ ushort Xb[64 * LS];
    __shared__ ushort Hb[64 * LS];

    const int tid  = threadIdx.x;
    const int lane = tid & 63;
    const int wv   = tid >> 6;
    const int col  = lane & 15, quad = lane >> 4;
    const int nb   = blockIdx.x * 64;

    float bG4[4];
    #pragma unroll
    for (int p = 0; p < 4; p++) bG4[p] = g_bsum[p * 160 + wv * 16 + col];

    for (int i = tid; i < 64 * LS; i += 640) Hb[i] = 0;

    float c_st[4][4];
    #pragma unroll
    for (int m = 0; m < 4; m++)
        #pragma unroll
        for (int r = 0; r < 4; r++) c_st[m][r] = 0.f;

    unsigned hn[4][2];

    const int grow  = tid / 10;
    const int gpart = tid - grow * 10;
    const int node_g = nb + grow;
    const int sbase = (node_g < N_NODES ? node_g : 0) * DEG;

    u32x4 P0, P1;
    {
        int s = edge_src[sbase];
        const u32x4* sp = (const u32x4*)(g_hin + s * F_DIM);
        P0 = sp[gpart]; P1 = sp[gpart + 10];
    }
    int snext = edge_src[sbase + 1];

    #pragma unroll 1
    for (int t = 0; t < NSTEP; t++) {
        if (t > 0) {
            #pragma unroll
            for (int m = 0; m < 4; m++)
                #pragma unroll
                for (int k = 0; k < 2; k++) {
                    int a = (m * 16 + quad * 4 + 2 * k) * LS + wv * 16 + col;
                    unsigned pk = hn[m][k];
                    Hb[a]      = (ushort)pk;
                    Hb[a + LS] = (ushort)(pk >> 16);
                }
        }
        {
            u32x4* dp = (u32x4*)(Xb + grow * LS);
            dp[gpart] = P0; dp[gpart + 10] = P1;
        }
        __syncthreads();

        {
            const u32x4* sp = (t < NSTEP - 1)
                ? (const u32x4*)(g_hin + snext * F_DIM)
                : (const u32x4*)(g_hin + (node_g < N_NODES ? node_g : 0) * F_DIM);
            P0 = sp[gpart]; P1 = sp[gpart + 10];
            snext = edge_src[sbase + ((t + 2 < DEG) ? t + 2 : 0)];
        }

        f32x4 acc[4][4];
        #pragma unroll
        for (int m = 0; m < 4; m++)
            #pragma unroll
            for (int p = 0; p < 4; p++)
                acc[m][p] = (f32x4){bG4[p], bG4[p], bG4[p], bG4[p]};

        const u32x4* wq = (const u32x4*)g_wfrag + wv * 40 * 64 + lane;
        #pragma unroll
        for (int kc = 0; kc < 10; kc++) {
            bf16x8 bfr[4];
            #pragma unroll
            for (int p = 0; p < 4; p++) {
                u32x4 u = wq[(kc * 4 + p) * 64];
                bfr[p] = *(const bf16x8*)&u;
            }
            const ushort* ab = ((kc < 5) ? (Xb + kc * 32) : (Hb + (kc - 5) * 32))
                               + col * LS + quad * 8;
            bf16x8 afr[4];
            #pragma unroll
            for (int m = 0; m < 4; m++)
                afr[m] = *(const bf16x8*)(ab + m * (16 * LS));
            #pragma unroll
            for (int m = 0; m < 4; m++)
                #pragma unroll
                for (int p = 0; p < 4; p++)
                    acc[m][p] = __builtin_amdgcn_mfma_f32_16x16x32_bf16(
                        afr[m], bfr[p], acc[m][p], 0, 0, 0);
        }
        #pragma unroll
        for (int m = 0; m < 4; m++) {
            #pragma unroll
            for (int k = 0; k < 2; k++) {
                unsigned pk = 0;
                #pragma unroll
                for (int h2 = 0; h2 < 2; h2++) {
                    int r = 2 * k + h2;
                    float c = sigmoid_fast(acc[m][1][r]) * c_st[m][r]
                            + sigmoid_fast(acc[m][0][r]) * tanh_fast(acc[m][2][r]);
                    c_st[m][r] = c;
                    float h = sigmoid_fast(acc[m][3][r]) * tanh_fast(c);
                    pk |= ((unsigned)f2bf(h)) << (16 * h2);
                }
                hn[m][k] = pk;
            }
        }
        __syncthreads();
    }

    #pragma unroll
    for (int m = 0; m < 4; m++)
        #pragma unroll
        for (int k = 0; k < 2; k++) {
            int a = (m * 16 + quad * 4 + 2 * k) * LS + wv * 16 + col;
            unsigned pk = hn[m][k];
            Hb[a]      = (ushort)pk;
            Hb[a + LS] = (ushort)(pk >> 16);
        }
    {
        u32x4* dp = (u32x4*)(Xb + grow * LS);
        dp[gpart] = P0; dp[gpart + 10] = P1;
    }
    __syncthreads();

    if (wv < 8) {
        const int m = wv & 3, pb = (wv >> 2) * 4;
        f32x4 acc[4];
        #pragma unroll
        for (int p = 0; p < 4; p++) {
            float b = bl[(pb + p) * 16 + col];
            acc[p] = (f32x4){b, b, b, b};
        }
        const u32x4* wq2 = (const u32x4*)g_wlrfrag + lane;
        #pragma unroll
        for (int kc = 0; kc < 10; kc++) {
            bf16x8 bfr[4];
            #pragma unroll
            for (int p = 0; p < 4; p++) {
                u32x4 u = wq2[(kc * 8 + pb + p) * 64];
                bfr[p] = *(const bf16x8*)&u;
            }
            const ushort* ab = ((kc < 5) ? (Hb + kc * 32) : (Xb + (kc - 5) * 32))
                               + (m * 16 + col) * LS + quad * 8;
            bf16x8 afr = *(const bf16x8*)ab;
            #pragma unroll
            for (int p = 0; p < 4; p++)
                acc[p] = __builtin_amdgcn_mfma_f32_16x16x32_bf16(afr, bfr[p], acc[p], 0, 0, 0);
        }
        #pragma unroll
        for (int p = 0; p < 4; p++) {
            int ocol = (pb + p) * 16 + col;
            #pragma unroll
            for (int r = 0; r < 4; r++) {
                int node = nb + m * 16 + quad * 4 + r;
                if (node < N_NODES) {
                    float v = acc[p][r];
                    out[node * OUT_CH + ocol] = v > 0.f ? v : 0.f;
                }
            }
        }
    }
}

extern "C" void kernel_launch(void* const* d_in, const int* in_sizes, int n_in,
                              void* d_out, int out_size, void* d_ws, size_t ws_size,
                              hipStream_t stream)
{
    const float* x      = (const float*)d_in[0];
    const int*   tids   = (const int*)  d_in[1];
    const int*   esrc   = (const int*)  d_in[2];   // edge_index[0] = src (dst sorted, DEG each)
    const float* emb    = (const float*)d_in[3];
    const float* Wih    = (const float*)d_in[4];
    const float* Whh    = (const float*)d_in[5];
    const float* bih    = (const float*)d_in[6];
    const float* bhh    = (const float*)d_in[7];
    const float* Wl     = (const float*)d_in[8];
    const float* blin   = (const float*)d_in[9];
    const float* Wr     = (const float*)d_in[10];
    float* out = (float*)d_out;

    hipLaunchKernelGGL(pack_kernel, dim3(123), dim3(256), 0, stream,
                       Wih, Whh, bih, bhh, Wl, Wr);
    hipLaunchKernelGGL(build_hin, dim3((N_NODES * F_DIM + 255) / 256), dim3(256), 0, stream,
                       x, tids, emb);

    // 43008 (Xb+Hb single buffers) + 112640 (11 resident frags) = 155648 B
    const int dbShmem = (2 * 64 * LS + NRES * 10 * 64 * 8) * (int)sizeof(ushort);
    (void)hipFuncSetAttribute((const void*)lstm_sage_r11,
                              hipFuncAttributeMaxDynamicSharedMemorySize, dbShmem);
    hipFuncAttributes fa;
    bool dbOk = (hipFuncGetAttributes(&fa, (const void*)lstm_sage_r11) == hipSuccess) &&
                (fa.maxDynamicSharedSizeBytes >= dbShmem);

    if (dbOk) {
        hipLaunchKernelGGL(lstm_sage_r11, dim3((N_NODES + 63) / 64), dim3(640),
                           dbShmem, stream, esrc, blin, out);
    } else {
        hipLaunchKernelGGL(lstm_sage_sb, dim3((N_NODES + 63) / 64), dim3(640),
                           0, stream, esrc, blin, out);
    }
}